// Round 10
// baseline (150.252 us; speedup 1.0000x reference)
//
#include <hip/hip_runtime.h>
#include <hip/hip_bf16.h>
#include <stdint.h>

#define B_ 4
#define S_ 1024
#define E_ 8
#define DE_ 128
#define SCALE_ 0.03125f   // 1/sqrt(1024)

typedef __attribute__((ext_vector_type(8))) short short8;
typedef __attribute__((ext_vector_type(4))) float f32x4;
typedef unsigned short ushort_t;
typedef unsigned int uint32;

__device__ __forceinline__ ushort_t f2bf(float f) {
    uint32 u = __float_as_uint(f);
    uint32 r = u + 0x7fffu + ((u >> 16) & 1u);   // round-to-nearest-even
    return (ushort_t)(r >> 16);
}

// Async global->LDS DMA, 16B/lane. LDS dst = wave-uniform base + lane*16.
#define GLOAD_LDS16(g, l) __builtin_amdgcn_global_load_lds( \
    (const __attribute__((address_space(1))) unsigned int*)(g), \
    (__attribute__((address_space(3))) unsigned int*)(l), 16, 0, 0)

// Stage 16 rows x 128 bf16 (4 KB), XOR-swizzled 16B-chunk order.
__device__ __forceinline__ void stage16(const ushort_t* __restrict__ g,
                                        size_t stride, ushort_t* lds,
                                        int w, int lane) {
    int cb = w << 6;
    int ch = cb + lane;
    int r = ch >> 4, c = ch & 15;
    GLOAD_LDS16(g + (size_t)r * stride + ((c ^ (r & 7)) << 3),
                lds + ((size_t)cb << 3));
}
// Stage 128 rows x 128 bf16 (32 KB).
__device__ __forceinline__ void stage128(const ushort_t* __restrict__ g,
                                         size_t stride, ushort_t* lds,
                                         int w, int lane) {
    #pragma unroll
    for (int j = 0; j < 8; ++j) {
        int cb = (w * 8 + j) << 6;
        int ch = cb + lane;
        int r = ch >> 4, c = ch & 15;
        GLOAD_LDS16(g + (size_t)r * stride + ((c ^ (r & 7)) << 3),
                    lds + ((size_t)cb << 3));
    }
}
// Read one MFMA frag (16B) from a swizzled 128-ush-pitch tile.
__device__ __forceinline__ short8 fld(const ushort_t* lds, int row, int c) {
    return *(const short8*)(lds + (((row << 4) + (c ^ (row & 7))) << 3));
}

__device__ __forceinline__ void top2(const float* rp, int& i1, int& i2) {
    float v1 = rp[0]; i1 = 0;
    #pragma unroll
    for (int i = 1; i < 8; ++i) { float v = rp[i]; if (v > v1) { v1 = v; i1 = i; } }
    float v2 = -1e30f; i2 = 0;
    #pragma unroll
    for (int i = 0; i < 8; ++i) {
        if (i == i1) continue;
        float v = rp[i]; if (v > v2) { v2 = v; i2 = i; }
    }
}

// ---------------------------------------------------------------------------
// Kernel 1: prep. Q,K fp32 -> bf16 [B][E][S][DE] (em-active planes);
// V -> bf16 transposed Vt [B][E][DE][S] (top-2 planes); zero-fill out
// slices of non-top2 experts. Grid (16 sc64, 8 e, 4 b).
// ---------------------------------------------------------------------------
__global__ __launch_bounds__(256) void prep_kernel(
        const float* __restrict__ Q, const float* __restrict__ K,
        const float* __restrict__ V, const float* __restrict__ route,
        const int* __restrict__ em,
        ushort_t* __restrict__ Qb, ushort_t* __restrict__ Kb,
        ushort_t* __restrict__ Vt, float* __restrict__ out) {
    __shared__ ushort_t tile[64][130];
    const int tid = threadIdx.x;
    const int sc = blockIdx.x, e = blockIdx.y, b = blockIdx.z;
    const int s0 = sc * 64;
    const size_t plane = ((size_t)(b * 8 + e)) << 17;

    const bool ak = em[e * B_ + b] != 0;
    int i1, i2; top2(route + b * 8, i1, i2);
    const bool av = (e == i1) || (e == i2);

    if (!av) {      // zero this expert's output slice (64 rows x 128)
        #pragma unroll
        for (int i = 0; i < 8; ++i) {
            int idx = tid + i * 256, r = idx >> 5, c4 = idx & 31;
            *(float4*)(out + (((size_t)(b * 1024 + s0 + r)) << 10) + (e << 7) + (c4 << 2))
                = make_float4(0.f, 0.f, 0.f, 0.f);
        }
    }
    if (ak) {
        #pragma unroll
        for (int i = 0; i < 8; ++i) {
            int idx = tid + i * 256, r = idx >> 5, c4 = idx & 31;
            size_t in_off = ((size_t)(b * 1024 + s0 + r) << 10) + (e << 7) + (c4 << 2);
            float4 q = *(const float4*)(Q + in_off);
            float4 k = *(const float4*)(K + in_off);
            size_t oo = plane + (((size_t)(s0 + r)) << 7) + (c4 << 2);
            *(ushort4*)(Qb + oo) = make_ushort4(f2bf(q.x), f2bf(q.y), f2bf(q.z), f2bf(q.w));
            *(ushort4*)(Kb + oo) = make_ushort4(f2bf(k.x), f2bf(k.y), f2bf(k.z), f2bf(k.w));
        }
    }
    if (av) {
        #pragma unroll
        for (int i = 0; i < 8; ++i) {
            int idx = tid + i * 256, r = idx >> 5, c4 = idx & 31;
            size_t in_off = ((size_t)(b * 1024 + s0 + r) << 10) + (e << 7) + (c4 << 2);
            float4 v = *(const float4*)(V + in_off);
            ushort_t* p = &tile[r][c4 << 2];
            p[0] = f2bf(v.x); p[1] = f2bf(v.y); p[2] = f2bf(v.z); p[3] = f2bf(v.w);
        }
        __syncthreads();
        #pragma unroll
        for (int i = 0; i < 4; ++i) {
            int item = tid + i * 256, d = item & 127, sg = item >> 7;
            union { uint4 q; ushort_t u[8]; } tmp;
            #pragma unroll
            for (int j = 0; j < 8; ++j) tmp.u[j] = tile[sg * 8 + j][d];
            *(uint4*)(Vt + plane + (((size_t)d) << 10) + s0 + (sg << 3)) = tmp.q;
        }
    }
}

// ---------------------------------------------------------------------------
// Kernel 2: attn_mega. One block per (16-row s-strip, b) = 256 blocks.
// Phase 1 (per active expert): stream K plane (8 x 32KB dbuf DMA chunks),
//   QK MFMA -> exp -> p strip in regs (64 f32/lane), lsum via LDS reduce,
//   aacc += p/l (combined attn strip in regs).
// Phase 2: attn strip -> LDS bf16; PV over top-2 experts, V chunks through
//   the same double buffer. All intermediates stay on-chip.
// ---------------------------------------------------------------------------
__global__ __launch_bounds__(256, 1) void attn_mega(
        const ushort_t* __restrict__ Qb, const ushort_t* __restrict__ Kb,
        const ushort_t* __restrict__ Vt, const float* __restrict__ route,
        const int* __restrict__ em, float* __restrict__ out) {

    __shared__ __align__(16) ushort_t kt[2][128 * 128];   // 64 KB (K, then V)
    __shared__ __align__(16) ushort_t qt[2][16 * 128];    // 8 KB
    __shared__ __align__(16) ushort_t attnL[16 * 1024];   // 32 KB
    __shared__ float red[4][16];

    const int stile = blockIdx.x, b = blockIdx.y;
    const int s0 = stile * 16;
    const int tid = threadIdx.x;
    const int w = tid >> 6, lane = tid & 63;
    const int quad = lane >> 4, l16 = lane & 15;

    uint32 epack = 0; int ne = 0;
    #pragma unroll
    for (int e = 0; e < 8; ++e)
        if (em[e * B_ + b] != 0) { epack |= (uint32)e << (3 * ne); ++ne; }
    int i1, i2; top2(route + b * 8, i1, i2);

    // combined attn strip accumulator: t = c*128 + w*32 + n*16 + l16,
    // rows quad*4+r  (64 fp32/lane)
    f32x4 aacc[8][2];
    #pragma unroll
    for (int c = 0; c < 8; ++c)
        #pragma unroll
        for (int n = 0; n < 2; ++n) aacc[c][n] = (f32x4){0.f, 0.f, 0.f, 0.f};

    if (ne > 0) {
        {   // initial stage: Q_e0 + K_e0 chunk0
            int e0 = epack & 7;
            size_t pl = ((size_t)(b * 8 + e0)) << 17;
            stage16(Qb + pl + ((size_t)s0 << 7), 128, qt[0], w, lane);
            stage128(Kb + pl, 128, kt[0], w, lane);
        }
        __syncthreads();

        for (int i = 0; i < ne; ++i) {
            int e = (epack >> (3 * i)) & 7;
            size_t pl = ((size_t)(b * 8 + e)) << 17;

            short8 af[4];
            #pragma unroll
            for (int kk = 0; kk < 4; ++kk)
                af[kk] = fld(qt[i & 1], l16, kk * 4 + quad);

            float rsum[4] = {0.f, 0.f, 0.f, 0.f};
            f32x4 pstr[8][2];

            #pragma unroll
            for (int c = 0; c < 8; ++c) {
                int g = i * 8 + c;
                if (c < 7) {
                    stage128(Kb + pl + (((size_t)(c + 1)) << 14), 128,
                             kt[(g + 1) & 1], w, lane);
                } else if (i + 1 < ne) {
                    int en = (epack >> (3 * (i + 1))) & 7;
                    size_t pln = ((size_t)(b * 8 + en)) << 17;
                    stage16(Qb + pln + ((size_t)s0 << 7), 128, qt[(i + 1) & 1], w, lane);
                    stage128(Kb + pln, 128, kt[(g + 1) & 1], w, lane);
                }
                const ushort_t* kb = kt[g & 1];
                f32x4 sacc[2];
                sacc[0] = (f32x4){0.f, 0.f, 0.f, 0.f};
                sacc[1] = (f32x4){0.f, 0.f, 0.f, 0.f};
                #pragma unroll
                for (int n = 0; n < 2; ++n)
                    #pragma unroll
                    for (int kk = 0; kk < 4; ++kk) {
                        short8 bf = fld(kb, w * 32 + n * 16 + l16, kk * 4 + quad);
                        sacc[n] = __builtin_amdgcn_mfma_f32_16x16x32_bf16(
                            af[kk], bf, sacc[n], 0, 0, 0);
                    }
                #pragma unroll
                for (int n = 0; n < 2; ++n)
                    #pragma unroll
                    for (int r = 0; r < 4; ++r) {
                        float p = __expf(sacc[n][r] * SCALE_);
                        pstr[c][n][r] = p;
                        rsum[r] += p;
                    }
                __syncthreads();
            }

            // row sums: over l16 (t-cols), then across waves via LDS
            #pragma unroll
            for (int off = 1; off < 16; off <<= 1)
                #pragma unroll
                for (int r = 0; r < 4; ++r)
                    rsum[r] += __shfl_xor(rsum[r], off, 64);
            if (l16 == 0) {
                #pragma unroll
                for (int r = 0; r < 4; ++r) red[w][quad * 4 + r] = rsum[r];
            }
            __syncthreads();
            float rinv[4];
            #pragma unroll
            for (int r = 0; r < 4; ++r)
                rinv[r] = 1.0f / (red[0][quad * 4 + r] + red[1][quad * 4 + r] +
                                  red[2][quad * 4 + r] + red[3][quad * 4 + r]);
            #pragma unroll
            for (int c = 0; c < 8; ++c)
                #pragma unroll
                for (int n = 0; n < 2; ++n)
                    #pragma unroll
                    for (int r = 0; r < 4; ++r)
                        aacc[c][n][r] += pstr[c][n][r] * rinv[r];
        }
    }

    // ---- attn strip -> LDS (bf16, chunk-xor swizzled, pitch 1024) ----
    #pragma unroll
    for (int c = 0; c < 8; ++c)
        #pragma unroll
        for (int n = 0; n < 2; ++n)
            #pragma unroll
            for (int r = 0; r < 4; ++r) {
                int row = quad * 4 + r;
                int t = c * 128 + w * 32 + n * 16 + l16;
                int ct = t >> 3, lo = t & 7;
                attnL[(row << 10) + (((ct ^ (row & 7)) << 3) | lo)] =
                    f2bf(aacc[c][n][r]);
            }
    // prefetch V(sel0, chunk0) while attn writes drain
    stage128(Vt + (((size_t)(b * 8 + i1)) << 17), 1024, kt[0], w, lane);
    __syncthreads();

    // ---- PV over top-2 experts ----
    int selE[2] = {i1, i2};
    f32x4 oacc[2][2];
    #pragma unroll
    for (int s = 0; s < 2; ++s)
        #pragma unroll
        for (int n = 0; n < 2; ++n) oacc[s][n] = (f32x4){0.f, 0.f, 0.f, 0.f};

    for (int sel = 0; sel < 2; ++sel) {
        size_t vpl = ((size_t)(b * 8 + selE[sel])) << 17;
        #pragma unroll
        for (int c = 0; c < 8; ++c) {
            int g = sel * 8 + c;
            if (c < 7)
                stage128(Vt + vpl + ((c + 1) * 128), 1024, kt[(g + 1) & 1], w, lane);
            else if (sel == 0)
                stage128(Vt + (((size_t)(b * 8 + selE[1])) << 17), 1024,
                         kt[(g + 1) & 1], w, lane);
            const ushort_t* vb = kt[g & 1];
            short8 af2[4];
            #pragma unroll
            for (int kk = 0; kk < 4; ++kk) {
                int ct = c * 16 + kk * 4 + quad;
                af2[kk] = *(const short8*)&attnL[(l16 << 10) + (((ct ^ (l16 & 7)) << 3))];
            }
            #pragma unroll
            for (int n = 0; n < 2; ++n)
                #pragma unroll
                for (int kk = 0; kk < 4; ++kk) {
                    short8 bf = fld(vb, w * 32 + n * 16 + l16, kk * 4 + quad);
                    oacc[sel][n] = __builtin_amdgcn_mfma_f32_16x16x32_bf16(
                        af2[kk], bf, oacc[sel][n], 0, 0, 0);
                }
            __syncthreads();
        }
    }

    #pragma unroll
    for (int sel = 0; sel < 2; ++sel)
        #pragma unroll
        for (int n = 0; n < 2; ++n)
            #pragma unroll
            for (int r = 0; r < 4; ++r)
                out[(((size_t)(b * 1024 + s0 + quad * 4 + r)) << 10)
                    + selE[sel] * 128 + w * 32 + n * 16 + l16] = oacc[sel][n][r];
}

// ---------------------------------------------------------------------------
extern "C" void kernel_launch(void* const* d_in, const int* in_sizes, int n_in,
                              void* d_out, int out_size, void* d_ws, size_t ws_size,
                              hipStream_t stream) {
    const float* Q     = (const float*)d_in[0];
    const float* K     = (const float*)d_in[1];
    const float* V     = (const float*)d_in[2];
    const float* route = (const float*)d_in[3];
    const int*   em    = (const int*)d_in[4];
    float* out = (float*)d_out;

    const size_t NB = (size_t)B_ * E_ * S_ * DE_;     // 4.19M elems
    ushort_t* Qb = (ushort_t*)d_ws;
    ushort_t* Kb = Qb + NB;
    ushort_t* Vt = Kb + NB;

    dim3 gp(16, 8, 4);
    prep_kernel<<<gp, 256, 0, stream>>>(Q, K, V, route, em, Qb, Kb, Vt, out);
    dim3 gm(64, 4);
    attn_mega<<<gm, 256, 0, stream>>>(Qb, Kb, Vt, route, em, out);
}

// Round 11
// 135.451 us; speedup vs baseline: 1.1093x; 1.1093x over previous
//
#include <hip/hip_runtime.h>
#include <hip/hip_bf16.h>
#include <stdint.h>

#define B_ 4
#define S_ 1024
#define E_ 8
#define DE_ 128
#define SCALE_ 0.03125f   // 1/sqrt(1024)

typedef __attribute__((ext_vector_type(8))) short short8;
typedef __attribute__((ext_vector_type(4))) float f32x4;
typedef unsigned short ushort_t;
typedef unsigned int uint32;
typedef unsigned long long u64;
typedef unsigned char uchar;

__device__ __forceinline__ ushort_t f2bf(float f) {
    uint32 u = __float_as_uint(f);
    uint32 r = u + 0x7fffu + ((u >> 16) & 1u);
    return (ushort_t)(r >> 16);
}

// fp32 -> fp8 e4m3fn, RNE, saturating. Manual (no header dependency).
__device__ __forceinline__ uchar f2fp8(float f) {
    float a = fminf(fmaxf(f, -448.f), 448.f);
    uint32 u = __float_as_uint(a);
    uint32 s = (u >> 31) << 7;
    int ex = (int)((u >> 23) & 0xff);
    uint32 man = u & 0x7fffff;
    int e8 = ex - 127 + 7;
    if (e8 >= 1) {
        uint32 m = man >> 20;
        uint32 rem = man & 0xfffff;
        if (rem > 0x80000u || (rem == 0x80000u && (m & 1))) ++m;
        if (m == 8) { m = 0; ++e8; }
        if (e8 > 15) { e8 = 15; m = 6; }          // saturate to 448
        return (uchar)(s | ((uint32)e8 << 3) | m);
    } else {
        int m = (int)rintf(fabsf(a) * 512.f);     // subnormal units 2^-9
        if (m > 7) m = 7;
        return (uchar)(s | (uint32)m);
    }
}

// Async global->LDS DMA, 16B/lane. LDS dst = wave-uniform base + lane*16.
#define GLOAD_LDS16(g, l) __builtin_amdgcn_global_load_lds( \
    (const __attribute__((address_space(1))) unsigned int*)(g), \
    (__attribute__((address_space(3))) unsigned int*)(l), 16, 0, 0)

// --- staging (512-thread blocks). Swizzle: 16B chunk c of row r stored at
// physical slot (c&~7)|((c&7)^(r&7)). DMA fetches logical chunk for slot u.
// K/Q fp8 tiles: rowBytes=128 (8 chunks). V bf16 tiles: rowBytes=256 (16).
__device__ __forceinline__ void stageK32(const uchar* g, uchar* lds, int tid) {
    // 256 rows x 128B contiguous (32 KB)
    #pragma unroll
    for (int k2 = 0; k2 < 4; ++k2) {
        int u = tid + k2 * 512;
        int r = u >> 3, c = u & 7;
        int cc = c ^ (r & 7);
        GLOAD_LDS16(g + r * 128 + (cc << 4), lds + (u << 4));
    }
}
__device__ __forceinline__ void stageV32(const uchar* g, uchar* lds, int tid) {
    // 128 rows x 256B, row stride 2048B (32 KB)
    #pragma unroll
    for (int k2 = 0; k2 < 4; ++k2) {
        int u = tid + k2 * 512;
        int r = u >> 4, c = u & 15;
        int cc = (c & 8) | ((c & 7) ^ (r & 7));
        GLOAD_LDS16(g + (size_t)r * 2048 + (cc << 4), lds + (u << 4));
    }
}
__device__ __forceinline__ void stageQ(const uchar* g, uchar* lds, int tid) {
    // 16 rows x 128B (2 KB), waves 0-1 only
    if (tid < 128) {
        int r = tid >> 3, c = tid & 7;
        int cc = c ^ (r & 7);
        GLOAD_LDS16(g + r * 128 + (cc << 4), lds + (tid << 4));
    }
}
// fp8 frag read: 8 bytes of row, d-window kk*32 + quad*8
__device__ __forceinline__ u64 fld8(const uchar* lds, int row, int kk, int quad) {
    int c = kk * 2 + (quad >> 1);
    int phys = c ^ (row & 7);
    return *(const u64*)(lds + row * 128 + (phys << 4) + ((quad & 1) << 3));
}
// V bf16 B-frag: 16B of row (d), t-window kk*32 + quad*8 elems
__device__ __forceinline__ short8 fldv(const uchar* lds, int row, int kk, int quad) {
    int c = kk * 4 + quad;
    int phys = (c & 8) | ((c & 7) ^ (row & 7));
    return *(const short8*)(lds + (size_t)row * 256 + (phys << 4));
}

__device__ __forceinline__ void top2(const float* rp, int& i1, int& i2) {
    float v1 = rp[0]; i1 = 0;
    #pragma unroll
    for (int i = 1; i < 8; ++i) { float v = rp[i]; if (v > v1) { v1 = v; i1 = i; } }
    float v2 = -1e30f; i2 = 0;
    #pragma unroll
    for (int i = 0; i < 8; ++i) {
        if (i == i1) continue;
        float v = rp[i]; if (v > v2) { v2 = v; i2 = i; }
    }
}

// ---------------------------------------------------------------------------
// Kernel 1: prep. Q,K fp32 -> fp8 e4m3 [B][E][S][DE] (em-active planes);
// V -> bf16 transposed Vt [B][E][DE][S] (top-2 planes); zero-fill non-top2
// out slices. Grid (16 sc64, 8 e, 4 b), 256 threads.
// ---------------------------------------------------------------------------
__global__ __launch_bounds__(256) void prep_kernel(
        const float* __restrict__ Q, const float* __restrict__ K,
        const float* __restrict__ V, const float* __restrict__ route,
        const int* __restrict__ em,
        uchar* __restrict__ Qb, uchar* __restrict__ Kb,
        ushort_t* __restrict__ Vt, float* __restrict__ out) {
    __shared__ ushort_t tile[64][130];
    const int tid = threadIdx.x;
    const int sc = blockIdx.x, e = blockIdx.y, b = blockIdx.z;
    const int s0 = sc * 64;
    const size_t plane8 = ((size_t)(b * 8 + e)) << 17;   // bytes (fp8)

    const bool ak = em[e * B_ + b] != 0;
    int i1, i2; top2(route + b * 8, i1, i2);
    const bool av = (e == i1) || (e == i2);

    if (!av) {
        #pragma unroll
        for (int i = 0; i < 8; ++i) {
            int idx = tid + i * 256, r = idx >> 5, c4 = idx & 31;
            *(float4*)(out + (((size_t)(b * 1024 + s0 + r)) << 10) + (e << 7) + (c4 << 2))
                = make_float4(0.f, 0.f, 0.f, 0.f);
        }
    }
    if (ak) {
        #pragma unroll
        for (int i = 0; i < 2; ++i) {
            int u = tid + i * 256;              // 0..511: 16-elem groups
            int r = u >> 3, dg = u & 7;
            const float* qs = Q + ((size_t)(b * 1024 + s0 + r) << 10) + (e << 7) + (dg << 4);
            const float* ks = K + ((size_t)(b * 1024 + s0 + r) << 10) + (e << 7) + (dg << 4);
            union { uint4 w; uchar c[16]; } oq, ok;
            #pragma unroll
            for (int j = 0; j < 4; ++j) {
                float4 qv = ((const float4*)qs)[j];
                float4 kv = ((const float4*)ks)[j];
                oq.c[j*4+0] = f2fp8(qv.x); oq.c[j*4+1] = f2fp8(qv.y);
                oq.c[j*4+2] = f2fp8(qv.z); oq.c[j*4+3] = f2fp8(qv.w);
                ok.c[j*4+0] = f2fp8(kv.x); ok.c[j*4+1] = f2fp8(kv.y);
                ok.c[j*4+2] = f2fp8(kv.z); ok.c[j*4+3] = f2fp8(kv.w);
            }
            size_t oo = plane8 + ((size_t)(s0 + r) << 7) + (dg << 4);
            *(uint4*)(Qb + oo) = oq.w;
            *(uint4*)(Kb + oo) = ok.w;
        }
    }
    if (av) {
        #pragma unroll
        for (int i = 0; i < 8; ++i) {
            int idx = tid + i * 256, r = idx >> 5, c4 = idx & 31;
            size_t in_off = ((size_t)(b * 1024 + s0 + r) << 10) + (e << 7) + (c4 << 2);
            float4 v = *(const float4*)(V + in_off);
            ushort_t* p = &tile[r][c4 << 2];
            p[0] = f2bf(v.x); p[1] = f2bf(v.y); p[2] = f2bf(v.z); p[3] = f2bf(v.w);
        }
        __syncthreads();
        #pragma unroll
        for (int i = 0; i < 4; ++i) {
            int item = tid + i * 256, d = item & 127, sg = item >> 7;
            union { uint4 q; ushort_t u[8]; } tmp;
            #pragma unroll
            for (int j = 0; j < 8; ++j) tmp.u[j] = tile[sg * 8 + j][d];
            *(uint4*)(Vt + (((size_t)(b * 8 + e)) << 17) + (((size_t)d) << 10)
                      + s0 + (sg << 3)) = tmp.q;
        }
    }
}

// ---------------------------------------------------------------------------
// Kernel 2: attn_mega. Block = (16-row s-strip, b), 512 threads (8 waves).
// Phase 1 per active expert: fp8 QK via 4 x 32KB dbuf DMA chunks,
//   exp -> p strip in regs, lsum via LDS reduce, aacc += p/l.
// Phase 2: attn -> LDS bf16 (swizzled); PV over top-2 via bf16 MFMA,
//   V chunks through the same double buffer. Grid (64, 4) = 256 blocks.
// ---------------------------------------------------------------------------
__global__ __launch_bounds__(512, 1) void attn_mega(
        const uchar* __restrict__ Qb, const uchar* __restrict__ Kb,
        const ushort_t* __restrict__ Vt, const float* __restrict__ route,
        const int* __restrict__ em, float* __restrict__ out) {

    __shared__ __align__(16) uchar kt[2][32768];
    __shared__ __align__(16) uchar qt[2][2048];
    __shared__ __align__(16) uchar attnL[32768];       // 16 x 1024 bf16, swizzled
    __shared__ float red[8][16];

    const int stile = blockIdx.x, b = blockIdx.y;
    const int s0 = stile * 16;
    const int tid = threadIdx.x;
    const int w = tid >> 6, lane = tid & 63;
    const int quad = lane >> 4, l16 = lane & 15;

    uint32 epack = 0; int ne = 0;
    #pragma unroll
    for (int e = 0; e < 8; ++e)
        if (em[e * B_ + b] != 0) { epack |= (uint32)e << (3 * ne); ++ne; }
    int i1, i2; top2(route + b * 8, i1, i2);

    // t = c*256 + w*32 + n*16 + l16 ; rows quad*4+r
    f32x4 aacc[4][2];
    #pragma unroll
    for (int c = 0; c < 4; ++c)
        #pragma unroll
        for (int n = 0; n < 2; ++n) aacc[c][n] = (f32x4){0.f, 0.f, 0.f, 0.f};

    if (ne > 0) {
        int e0 = epack & 7;
        stageQ(Qb + (((size_t)(b * 8 + e0)) << 17) + ((size_t)s0 << 7), qt[0], tid);
        stageK32(Kb + (((size_t)(b * 8 + e0)) << 17), kt[0], tid);
        __syncthreads();

        for (int i = 0; i < ne; ++i) {
            int e = (epack >> (3 * i)) & 7;
            const uchar* kp = Kb + (((size_t)(b * 8 + e)) << 17);

            u64 af[4];
            #pragma unroll
            for (int kk = 0; kk < 4; ++kk) af[kk] = fld8(qt[i & 1], l16, kk, quad);

            float rsum[4] = {0.f, 0.f, 0.f, 0.f};
            f32x4 ps[4][2];

            #pragma unroll
            for (int c = 0; c < 4; ++c) {
                int g = i * 4 + c;
                if (c < 3) {
                    stageK32(kp + (size_t)(c + 1) * 32768, kt[(g + 1) & 1], tid);
                } else if (i + 1 < ne) {
                    int en = (epack >> (3 * (i + 1))) & 7;
                    stageQ(Qb + (((size_t)(b * 8 + en)) << 17) + ((size_t)s0 << 7),
                           qt[(i + 1) & 1], tid);
                    stageK32(Kb + (((size_t)(b * 8 + en)) << 17), kt[(g + 1) & 1], tid);
                } else {
                    stageV32((const uchar*)(Vt + (((size_t)(b * 8 + i1)) << 17)),
                             kt[(g + 1) & 1], tid);
                }
                const uchar* kb = kt[g & 1];
                #pragma unroll
                for (int n = 0; n < 2; ++n) {
                    f32x4 s = {0.f, 0.f, 0.f, 0.f};
                    int trow = w * 32 + n * 16 + l16;
                    #pragma unroll
                    for (int kk = 0; kk < 4; ++kk) {
                        u64 bf = fld8(kb, trow, kk, quad);
                        s = __builtin_amdgcn_mfma_f32_16x16x32_fp8_fp8(
                            (long)af[kk], (long)bf, s, 0, 0, 0);
                    }
                    #pragma unroll
                    for (int r = 0; r < 4; ++r) {
                        float p = __expf(s[r] * SCALE_);
                        ps[c][n][r] = p;
                        rsum[r] += p;
                    }
                }
                __syncthreads();
            }

            #pragma unroll
            for (int off = 1; off < 16; off <<= 1)
                #pragma unroll
                for (int r = 0; r < 4; ++r) rsum[r] += __shfl_xor(rsum[r], off, 64);
            if (l16 == 0) {
                #pragma unroll
                for (int r = 0; r < 4; ++r) red[w][quad * 4 + r] = rsum[r];
            }
            __syncthreads();
            float rinv[4];
            #pragma unroll
            for (int r = 0; r < 4; ++r) {
                float l = 0.f;
                #pragma unroll
                for (int ww = 0; ww < 8; ++ww) l += red[ww][quad * 4 + r];
                rinv[r] = 1.0f / l;
            }
            #pragma unroll
            for (int c = 0; c < 4; ++c)
                #pragma unroll
                for (int n = 0; n < 2; ++n)
                    #pragma unroll
                    for (int r = 0; r < 4; ++r)
                        aacc[c][n][r] += ps[c][n][r] * rinv[r];
        }
    } else {
        stageV32((const uchar*)(Vt + (((size_t)(b * 8 + i1)) << 17)), kt[0], tid);
    }

    // ---- attn strip -> LDS bf16 (swizzled 16B chunks) ----
    #pragma unroll
    for (int c = 0; c < 4; ++c)
        #pragma unroll
        for (int n = 0; n < 2; ++n)
            #pragma unroll
            for (int r = 0; r < 4; ++r) {
                int row = quad * 4 + r;
                int t = c * 256 + w * 32 + n * 16 + l16;
                int ct = t >> 3;
                int phys = (ct & ~7) | ((ct & 7) ^ (row & 7));
                *(ushort_t*)(attnL + row * 2048 + (phys << 4) + ((t & 7) << 1)) =
                    f2bf(aacc[c][n][r]);
            }
    __syncthreads();   // attnL visible; V(i1,0) DMA drained by barrier

    // ---- PV: wave w owns d-span w*16; eo outer, 8 x 128-t chunks each ----
    int selE[2] = {i1, i2};
    #pragma unroll
    for (int sel = 0; sel < 2; ++sel) {
        const uchar* vp = (const uchar*)(Vt + (((size_t)(b * 8 + selE[sel])) << 17));
        f32x4 oacc = {0.f, 0.f, 0.f, 0.f};
        #pragma unroll
        for (int c = 0; c < 8; ++c) {
            int g = ne * 4 + sel * 8 + c;
            if (c < 7)
                stageV32(vp + (size_t)(c + 1) * 256, kt[(g + 1) & 1], tid);
            else if (sel == 0)
                stageV32((const uchar*)(Vt + (((size_t)(b * 8 + selE[1])) << 17)),
                         kt[(g + 1) & 1], tid);
            const uchar* vb = kt[g & 1];
            #pragma unroll
            for (int kk = 0; kk < 4; ++kk) {
                int ct = c * 16 + kk * 4 + quad;
                int phys = (ct & ~7) | ((ct & 7) ^ (l16 & 7));
                short8 afr = *(const short8*)(attnL + l16 * 2048 + (phys << 4));
                short8 bfr = fldv(vb, w * 16 + l16, kk, quad);
                oacc = __builtin_amdgcn_mfma_f32_16x16x32_bf16(afr, bfr, oacc, 0, 0, 0);
            }
            __syncthreads();
        }
        #pragma unroll
        for (int r = 0; r < 4; ++r)
            out[(((size_t)(b * 1024 + s0 + quad * 4 + r)) << 10)
                + selE[sel] * 128 + w * 16 + l16] = oacc[r];
    }
}

// ---------------------------------------------------------------------------
extern "C" void kernel_launch(void* const* d_in, const int* in_sizes, int n_in,
                              void* d_out, int out_size, void* d_ws, size_t ws_size,
                              hipStream_t stream) {
    const float* Q     = (const float*)d_in[0];
    const float* K     = (const float*)d_in[1];
    const float* V     = (const float*)d_in[2];
    const float* route = (const float*)d_in[3];
    const int*   em    = (const int*)d_in[4];
    float* out = (float*)d_out;

    const size_t NB = (size_t)B_ * E_ * S_ * DE_;     // 4.19M elems
    uchar* Qb = (uchar*)d_ws;                         // fp8 planes (NB bytes)
    uchar* Kb = Qb + NB;
    ushort_t* Vt = (ushort_t*)(Kb + NB);              // bf16 (NB elems)

    dim3 gp(16, 8, 4);
    prep_kernel<<<gp, 256, 0, stream>>>(Q, K, V, route, em, Qb, Kb, Vt, out);
    dim3 gm(64, 4);
    attn_mega<<<gm, 512, 0, stream>>>(Qb, Kb, Vt, route, em, out);
}